// Round 1
// baseline (399.741 us; speedup 1.0000x reference)
//
#include <hip/hip_runtime.h>
#include <hip/hip_bf16.h>
#include <math.h>

#define HIDDEN   4096
#define NEXP     64
#define NTOK     16384
#define KCHUNKS  8
#define KC       (HIDDEN / KCHUNKS)   // 512 k per chunk
#define BK       32                   // k per LDS stage
#define BT       64                   // tokens per block
#define LDSS     68                   // padded LDS row stride (words); 68*4=272B, 16B-aligned rows

// ---------------- Kernel 1: split-K fp32 GEMM -> partial logits ----------------
// grid (256 token tiles, 8 k-chunks), block = 64 threads (1 wave).
// Per-thread 8x8 register tile: 64 FMA per k-step vs 4 ds_read_b128 -> VALU-bound.
__global__ __launch_bounds__(64, 2)
void gemm_partial(const float* __restrict__ x, const float* __restrict__ W,
                  float* __restrict__ part) {
    __shared__ float Xs[BK][LDSS];
    __shared__ float Ws[BK][LDSS];

    const int tid  = threadIdx.x;
    const int tile = blockIdx.x;       // token tile 0..255
    const int kc   = blockIdx.y;       // k chunk 0..7
    const int t0   = tile * BT;

    const int lrow = tid & 7;          // which float4 along k (0..7) for staging
    const int lcol = tid >> 3;         // which row group (0..7) for staging
    const int i    = tid & 7;          // token group (8 tokens) for compute
    const int j    = tid >> 3;         // expert group (8 experts) for compute

    float acc[8][8];
#pragma unroll
    for (int m = 0; m < 8; ++m)
#pragma unroll
        for (int e = 0; e < 8; ++e) acc[m][e] = 0.f;

    for (int kb = 0; kb < KC / BK; ++kb) {
        const int kg = kc * KC + kb * BK + lrow * 4;
        // stage X tile (64 tok x 32 k) and W tile (64 exp x 32 k), transposed into LDS [k][row]
#pragma unroll
        for (int p = 0; p < 8; ++p) {
            const int r = p * 8 + lcol;          // token / expert index in tile
            const float4 xv = *(const float4*)&x[(size_t)(t0 + r) * HIDDEN + kg];
            Xs[lrow * 4 + 0][r] = xv.x;
            Xs[lrow * 4 + 1][r] = xv.y;
            Xs[lrow * 4 + 2][r] = xv.z;
            Xs[lrow * 4 + 3][r] = xv.w;
            const float4 wv = *(const float4*)&W[(size_t)r * HIDDEN + kg];
            Ws[lrow * 4 + 0][r] = wv.x;
            Ws[lrow * 4 + 1][r] = wv.y;
            Ws[lrow * 4 + 2][r] = wv.z;
            Ws[lrow * 4 + 3][r] = wv.w;
        }
        __syncthreads();
#pragma unroll
        for (int kk = 0; kk < BK; ++kk) {
            const float4 xa = *(const float4*)&Xs[kk][i * 8];
            const float4 xb = *(const float4*)&Xs[kk][i * 8 + 4];
            const float4 wa = *(const float4*)&Ws[kk][j * 8];
            const float4 wb = *(const float4*)&Ws[kk][j * 8 + 4];
            const float xr[8] = {xa.x, xa.y, xa.z, xa.w, xb.x, xb.y, xb.z, xb.w};
            const float wr[8] = {wa.x, wa.y, wa.z, wa.w, wb.x, wb.y, wb.z, wb.w};
#pragma unroll
            for (int m = 0; m < 8; ++m)
#pragma unroll
                for (int e = 0; e < 8; ++e)
                    acc[m][e] = fmaf(xr[m], wr[e], acc[m][e]);
        }
        __syncthreads();
    }

    // write partial logits: part[kc][token][expert]
    float* dst = part + ((size_t)kc * NTOK + t0) * NEXP;
#pragma unroll
    for (int m = 0; m < 8; ++m) {
        const int tok = i * 8 + m;
#pragma unroll
        for (int h = 0; h < 2; ++h) {
            float4 o = make_float4(acc[m][h * 4 + 0], acc[m][h * 4 + 1],
                                   acc[m][h * 4 + 2], acc[m][h * 4 + 3]);
            *(float4*)&dst[(size_t)tok * NEXP + j * 8 + h * 4] = o;
        }
    }
}

// ---------------- Kernel 2: reduce partials + bias, softmax, top-2 ----------------
// One wave per token; lane = expert. Butterfly reductions, tie-break lower index.
__global__ __launch_bounds__(256)
void softmax_top2(const float* __restrict__ part, const float* __restrict__ bias,
                  float* __restrict__ out) {
    const int lane = threadIdx.x & 63;
    const int wid  = threadIdx.x >> 6;
    const int t    = blockIdx.x * 4 + wid;

    float l = bias[lane];
#pragma unroll
    for (int c = 0; c < KCHUNKS; ++c)
        l += part[((size_t)c * NTOK + t) * NEXP + lane];

    // wave max
    float m = l;
#pragma unroll
    for (int s = 32; s > 0; s >>= 1)
        m = fmaxf(m, __shfl_xor(m, s, 64));

    // softmax denominator (deterministic butterfly)
    float ssum = expf(l - m);
#pragma unroll
    for (int s = 32; s > 0; s >>= 1)
        ssum += __shfl_xor(ssum, s, 64);

    // top-1: max value, lower index wins ties
    float v1 = l; int i1 = lane;
#pragma unroll
    for (int s = 32; s > 0; s >>= 1) {
        float ov = __shfl_xor(v1, s, 64);
        int   oi = __shfl_xor(i1, s, 64);
        if (ov > v1 || (ov == v1 && oi < i1)) { v1 = ov; i1 = oi; }
    }
    // top-2: exclude i1
    float v2 = (lane == i1) ? -INFINITY : l;
    int   i2 = lane;
#pragma unroll
    for (int s = 32; s > 0; s >>= 1) {
        float ov = __shfl_xor(v2, s, 64);
        int   oi = __shfl_xor(i2, s, 64);
        if (ov > v2 || (ov == v2 && oi < i2)) { v2 = ov; i2 = oi; }
    }

    if (lane == 0) {
        const float inv = 1.0f / ssum;
        out[(size_t)t * 2 + 0] = inv;                    // exp(v1-m)=1 since v1==m
        out[(size_t)t * 2 + 1] = expf(v2 - m) * inv;
        out[(size_t)2 * NTOK + t * 2 + 0] = (float)i1;   // indices read back as float32
        out[(size_t)2 * NTOK + t * 2 + 1] = (float)i2;
    }
}

extern "C" void kernel_launch(void* const* d_in, const int* in_sizes, int n_in,
                              void* d_out, int out_size, void* d_ws, size_t ws_size,
                              hipStream_t stream) {
    const float* x  = (const float*)d_in[0];
    const float* W  = (const float*)d_in[1];
    const float* b  = (const float*)d_in[2];
    float* out  = (float*)d_out;
    float* part = (float*)d_ws;   // needs KCHUNKS*NTOK*NEXP*4 = 32 MB scratch

    dim3 g1(NTOK / BT, KCHUNKS);  // 256 x 8 = 2048 one-wave blocks
    gemm_partial<<<g1, 64, 0, stream>>>(x, W, part);
    softmax_top2<<<NTOK / 4, 256, 0, stream>>>(part, b, out);
}